// Round 12
// baseline (425.234 us; speedup 1.0000x reference)
//
#include <hip/hip_runtime.h>

#define B_ 16
#define C_ 64
#define H_ 128
#define W_ 256
#define K_ 9
#define KDIM_ (K_*C_)            // 576

typedef __attribute__((ext_vector_type(8))) short short8_t;
typedef __attribute__((ext_vector_type(4))) float f32x4;

static __device__ __forceinline__ float bf2f(unsigned short u) {
  union { unsigned int i; float f; } v; v.i = ((unsigned int)u) << 16; return v.f;
}
static __device__ __forceinline__ unsigned short f2bf(float f) {
  union { float f; unsigned int i; } v; v.f = f;
  unsigned int r = v.i + 0x7FFF + ((v.i >> 16) & 1);   // RNE
  return (unsigned short)(r >> 16);
}

// async global->LDS, 16B per lane; lds base wave-uniform, lanes fill +lane*16
static __device__ __forceinline__ void gload_lds16(const void* g, void* l) {
  __builtin_amdgcn_global_load_lds(
      (const __attribute__((address_space(1))) unsigned int*)g,
      (__attribute__((address_space(3))) unsigned int*)l, 16, 0, 0);
}

// All 4 weight tensors [co][ci][kk] fp32 -> A2 chunk layout (16B chunk = 8
// consecutive k for one co): A2[((k>>3)*64+co)*8 + (k&7)], k = kk*64+ci.
__global__ __launch_bounds__(256) void prep_w_all(const float* __restrict__ w0,
                                                  const float* __restrict__ w1,
                                                  const float* __restrict__ w2,
                                                  const float* __restrict__ w3,
                                                  unsigned short* __restrict__ A2) {
  int idx = blockIdx.x * 256 + threadIdx.x;
  if (idx >= C_ * KDIM_) return;
  int which = blockIdx.y;
  const float* w = (which == 0) ? w0 : (which == 1) ? w1 : (which == 2) ? w2 : w3;
  unsigned short* out = A2 + (size_t)which * (C_ * KDIM_);
  int co = idx / KDIM_, k = idx % KDIM_;
  int ci = k & 63, kk = k >> 6;
  out[((size_t)(k >> 3) * 64 + co) * 8 + (k & 7)] =
      f2bf(w[((size_t)co * C_ + ci) * K_ + kk]);
}

// fp32 NCHW -> bf16 ci-minor [b][h][w][ci]
__global__ __launch_bounds__(256) void transpose_in(const float* __restrict__ x,
                                                    unsigned short* __restrict__ Xt) {
  __shared__ float tile[64][65];
  const int w0 = blockIdx.x * 64, h = blockIdx.y, b = blockIdx.z;
  const int t = threadIdx.x;
#pragma unroll
  for (int rep = 0; rep < 16; ++rep) {
    int idx = rep * 256 + t;
    int ci = idx >> 6, wl = idx & 63;
    tile[ci][wl] = x[((size_t)(b * C_ + ci) * H_ + h) * W_ + w0 + wl];
  }
  __syncthreads();
#pragma unroll
  for (int rep = 0; rep < 8; ++rep) {
    int idx = rep * 256 + t;
    int wl = idx >> 5, cp = idx & 31;
    unsigned v = (unsigned)f2bf(tile[cp*2][wl]) | ((unsigned)f2bf(tile[cp*2+1][wl]) << 16);
    *(unsigned*)(Xt + ((size_t)(b * H_ + h) * W_ + w0 + wl) * C_ + cp * 2) = v;
  }
}

// [b][h][w][ci] bf16 -> fp32 NCHW (final output) — proven R4-R6 version
__global__ __launch_bounds__(256) void transpose_out(const unsigned short* __restrict__ F,
                                                     float* __restrict__ out) {
  __shared__ float tile[64][65];
  const int w0 = blockIdx.x * 64, h = blockIdx.y, b = blockIdx.z;
  const int t = threadIdx.x;
#pragma unroll
  for (int rep = 0; rep < 8; ++rep) {
    int idx = rep * 256 + t;
    int wl = idx >> 5, cp = idx & 31;
    unsigned v = *(const unsigned*)(F + ((size_t)(b * H_ + h) * W_ + w0 + wl) * C_ + cp * 2);
    tile[cp*2][wl]   = bf2f((unsigned short)v);
    tile[cp*2+1][wl] = bf2f((unsigned short)(v >> 16));
  }
  __syncthreads();
#pragma unroll
  for (int rep = 0; rep < 16; ++rep) {
    int idx = rep * 256 + t;
    int ci = idx >> 6, wl = idx & 63;
    out[((size_t)(b * C_ + ci) * H_ + h) * W_ + w0 + wl] = tile[ci][wl];
  }
}

// ===== fused2: fully fused conv(inner Q) + scan(outer P) on [b][P][Q][ci] =====
// 1 wave per block. Grid (QLEN/16, B, 4): wave owns 16 Q-positions x 16 co
// (co slice = blockIdx.z*16; z is slowest -> co-split copies share an XCD/L2).
// A slice (18 frags) in registers (72 VGPR, R4-proven). X rows staged into a
// private 8-row LDS ring (3KB/row, chunk-XOR swizzle via pre-swizzled global
// source), 3 row-pairs ahead; counted vmcnt(24) (6 loads + 2 stores per iter,
// R5-proven scheme), NO barriers. Carry y stays fp32 in registers.
// TRANS=1: output written transposed to [b][Q][P][ci] (layout-flip trick).
template<int PLEN, int QLEN, int REV, int TRANS>
__global__ __launch_bounds__(64, 1) void fused2(const unsigned short* __restrict__ X,
                                                unsigned short* __restrict__ Y,
                                                const unsigned short* __restrict__ A2,
                                                const float* __restrict__ bias,
                                                const unsigned short* __restrict__ ZP) {
  __shared__ __align__(16) char ring[8 * 3072];
  const int lane = threadIdx.x;
  const int llo = lane & 15, lhi = lane >> 4;
  const int q0 = blockIdx.x * 16;
  const int b  = blockIdx.y;
  const int cs = blockIdx.z;
  constexpr int NPAIR = PLEN / 2;

  // ---- A slice -> registers ----
  short8_t areg[18];
#pragma unroll
  for (int st = 0; st < 18; ++st)
    areg[st] = *(const short8_t*)(A2 + (size_t)((st*4 + lhi)*64 + cs*16 + llo) * 8);
  const float4 bv = *(const float4*)(bias + cs*16 + lhi*4);

  auto stageRow = [&](int i) {     // i = scan-order row index
    const int p = REV ? (PLEN - 1 - i) : i;
    char* dst = ring + (i & 7) * 3072;
    const int rr = lane >> 3, sl = lane & 7;
#pragma unroll
    for (int g = 0; g < 3; ++g) {
      int r = g*8 + rr;                       // staged position 0..23
      int chunk = sl ^ (r & 7);               // pre-swizzled source chunk
      int sq = q0 - 4 + r;
      const void* src = ((unsigned)sq < (unsigned)QLEN)
        ? (const void*)(X + ((size_t)(b*PLEN + p)*QLEN + sq)*64 + chunk*8)
        : (const void*)(ZP + sl*8);
      gload_lds16(src, dst + g*1024);
    }
  };

  auto convRow = [&](int i) -> f32x4 {
    const char* sp = ring + (i & 7) * 3072;
    f32x4 acc = {0.f,0.f,0.f,0.f};
#pragma unroll
    for (int st = 0; st < 18; ++st) {
      int r = llo + (st >> 1);
      int cg = (st & 1)*4 + lhi;
      short8_t f = *(const short8_t*)(sp + r*128 + ((cg ^ (r & 7)) << 4));
      acc = __builtin_amdgcn_mfma_f32_16x16x32_bf16(areg[st], f, acc, 0, 0, 0);
    }
    return acc;
  };

  float y0, y1, y2, y3;
  auto storeOut = [&](int i, uint2 v) {
    const int p = REV ? (PLEN - 1 - i) : i;
    const int q = q0 + llo;
    size_t off = TRANS ? (((size_t)(b*QLEN + q)*PLEN + p)*64)
                       : (((size_t)(b*PLEN + p)*QLEN + q)*64);
    *(uint2*)(Y + off + cs*16 + lhi*4) = v;
  };
  auto finRow = [&](int i, f32x4 acc) {
    y0 = fmaxf(acc[0] + bv.x + y0, 0.f);
    y1 = fmaxf(acc[1] + bv.y + y1, 0.f);
    y2 = fmaxf(acc[2] + bv.z + y2, 0.f);
    y3 = fmaxf(acc[3] + bv.w + y3, 0.f);
    unsigned lo, hi;
    asm("v_cvt_pk_bf16_f32 %0, %1, %2" : "=v"(lo) : "v"(y0), "v"(y1));
    asm("v_cvt_pk_bf16_f32 %0, %1, %2" : "=v"(hi) : "v"(y2), "v"(y3));
    uint2 ov; ov.x = lo; ov.y = hi;
    storeOut(i, ov);
  };

  // ---- prologue: stage rows 0..5, drain everything ----
  stageRow(0); stageRow(1); stageRow(2); stageRow(3); stageRow(4); stageRow(5);
  asm volatile("s_waitcnt vmcnt(0)" ::: "memory");

  // ---- pair 0 peeled: row0 passthrough + row1 conv ----
  {
    stageRow(6); stageRow(7);
    const int r0 = llo + 4;
    const int cc = cs*2 + (lhi >> 1);        // global 16B-chunk of this co slice
    uint2 v = *(const uint2*)(ring + r0*128 + ((cc ^ (r0 & 7)) << 4) + (lhi & 1)*8);
    y0 = bf2f((unsigned short)v.x); y1 = bf2f((unsigned short)(v.x >> 16));
    y2 = bf2f((unsigned short)v.y); y3 = bf2f((unsigned short)(v.y >> 16));
    storeOut(0, v);                          // boundary row copied bit-exact
    f32x4 a1 = convRow(1);
    finRow(1, a1);
  }

  // ---- main loop: one row-pair per iteration ----
  for (int i = 1; i < NPAIR; ++i) {
    if (i + 3 < NPAIR) {
      stageRow(2*i + 6); stageRow(2*i + 7);
      // pair i's 6 loads were issued 3 iters ago; since then exactly
      // 2 + 8 + 8 + 6 = 24 VMEM ops issued -> vmcnt(24) == pair ready.
      asm volatile("s_waitcnt vmcnt(24)" ::: "memory");
    } else {
      asm volatile("s_waitcnt vmcnt(0)" ::: "memory");
    }
    f32x4 aA = convRow(2*i);
    f32x4 aB = convRow(2*i + 1);
    finRow(2*i, aA);
    finRow(2*i + 1, aB);
  }
}

extern "C" void kernel_launch(void* const* d_in, const int* in_sizes, int n_in,
                              void* d_out, int out_size, void* d_ws, size_t ws_size,
                              hipStream_t stream) {
  const float* x    = (const float*)d_in[0];
  const float* w_ud = (const float*)d_in[1];
  const float* b_ud = (const float*)d_in[2];
  const float* w_du = (const float*)d_in[3];
  const float* b_du = (const float*)d_in[4];
  const float* w_lr = (const float*)d_in[5];
  const float* b_lr = (const float*)d_in[6];
  const float* w_rl = (const float*)d_in[7];
  const float* b_rl = (const float*)d_in[8];

  // ws: A[0,64M) Bb[64M,128M) Cc[128M,192M) A2 @192M, zeropage @192M+1M
  unsigned short* A  = (unsigned short*)d_ws;
  unsigned short* Bb = (unsigned short*)((char*)d_ws + 67108864);
  unsigned short* Cc = (unsigned short*)((char*)d_ws + 134217728);
  unsigned short* A2 = (unsigned short*)((char*)d_ws + 201326592);
  unsigned short* ZP = (unsigned short*)((char*)d_ws + 202375168);
  unsigned short* A2_ud = A2 + 0 * (C_ * KDIM_);
  unsigned short* A2_du = A2 + 1 * (C_ * KDIM_);
  unsigned short* A2_lr = A2 + 2 * (C_ * KDIM_);
  unsigned short* A2_rl = A2 + 3 * (C_ * KDIM_);

  hipMemsetAsync(ZP, 0, 1024, stream);

  dim3 pg((C_ * KDIM_ + 255) / 256, 4);
  prep_w_all<<<pg, 256, 0, stream>>>(w_ud, w_du, w_lr, w_rl, A2);

  transpose_in<<<dim3(4, H_, B_), 256, 0, stream>>>(x, A);

  // sweep 1 (ud): [b][h][w][ci], conv along w, scan fwd along h
  fused2<H_, W_, 0, 0><<<dim3(16, B_, 4), 64, 0, stream>>>(A,  Bb, A2_ud, b_ud, ZP);
  // sweep 2 (du): scan rev along h, write TRANSPOSED -> [b][w][h][ci]
  fused2<H_, W_, 1, 1><<<dim3(16, B_, 4), 64, 0, stream>>>(Bb, Cc, A2_du, b_du, ZP);
  // sweep 3 (lr): on flipped layout, conv along h (inner), scan fwd along w (outer)
  fused2<W_, H_, 0, 0><<<dim3(8, B_, 4), 64, 0, stream>>>(Cc, A, A2_lr, b_lr, ZP);
  // sweep 4 (rl): scan rev along w, write TRANSPOSED -> back to [b][h][w][ci]
  fused2<W_, H_, 1, 1><<<dim3(8, B_, 4), 64, 0, stream>>>(A, Bb, A2_rl, b_rl, ZP);

  transpose_out<<<dim3(4, H_, B_), 256, 0, stream>>>(Bb, (float*)d_out);
}